// Round 8
// baseline (245.288 us; speedup 1.0000x reference)
//
#include <hip/hip_runtime.h>
#include <stdint.h>

#define HIDN 128
#define EMBN 32
#define PCAP 16        // pair bucket row (Poisson(2): overflow ~0)
#define NCAP 64        // node bucket row (Poisson(16): overflow ~0)
#define PSEGSH 8       // pair bin = ed >> 8 (256 edges/bin; k_back pair block = 1 bin, x1 scan)
#define NSEGSH 7       // node bin = nd >> 7   (128 nodes/bin)
#define PSEG (1 << PSEGSH)
#define NSEG (1 << NSEGSH)
#define PBCAP 768      // entries/pair-bin cap (mean 512, +11 sigma)
#define NBCAP 2816     // entries/node-bin cap (mean 2048)
#define CHUNK 16384    // items per partition block (32/thread at 512 thr; coalesced bin stores)
#define MAXPB 1600     // >= PBINS (1563)

typedef __attribute__((ext_vector_type(8))) short bf16x8;
typedef __attribute__((ext_vector_type(4))) float f32x4;

// ---------- helpers ----------
__device__ __forceinline__ unsigned bf16r(float f) {   // fp32 -> bf16 bits, RNE
  unsigned u = __float_as_uint(f);
  return (u + 0x7FFFu + ((u >> 16) & 1u)) >> 16;
}
__device__ __forceinline__ unsigned pack2(float a, float b) {
  return bf16r(a) | (bf16r(b) << 16);
}
__device__ __forceinline__ float blo(unsigned u) { return __uint_as_float(u << 16); }
__device__ __forceinline__ float bhi(unsigned u) { return __uint_as_float(u & 0xFFFF0000u); }
__device__ __forceinline__ float4 f4fma(float s, float4 a, float4 b) {
  return make_float4(fmaf(s, a.x, b.x), fmaf(s, a.y, b.y), fmaf(s, a.z, b.z), fmaf(s, a.w, b.w));
}
__device__ __forceinline__ float4 f4max0(float4 a) {
  return make_float4(fmaxf(a.x, 0.f), fmaxf(a.y, 0.f), fmaxf(a.z, 0.f), fmaxf(a.w, 0.f));
}

// ---------- prep1: Wq'=W2@Wq, Wk'=W2@Wk, bqp; block 33: Wvsp/bvs; block 34: zero goff ----------
__global__ __launch_bounds__(256) void k_prep1(
    const float* __restrict__ W2, const float* __restrict__ b2,
    const float* __restrict__ Wq, const float* __restrict__ Wk, const float* __restrict__ Wv,
    float* __restrict__ Wqp, float* __restrict__ Wkp, float* __restrict__ bqp,
    float* __restrict__ Wvsp, float* __restrict__ bvs,
    int* __restrict__ goffP, int* __restrict__ goffN, int PBINS, int NBINS)
{
  __shared__ float swvs[HIDN * 4];
  int t = threadIdx.x;
  if (blockIdx.x == 34) {
    // zero bin offset arrays (replaces a hipMemsetAsync dispatch)
    for (int i = t; i < PBINS + NBINS; i += 256) {
      if (i < PBINS) goffP[i] = 0; else goffN[i - PBINS] = 0;
    }
    return;
  }
  if (blockIdx.x == 33) {
    for (int idx = t; idx < HIDN * 4; idx += 256) {
      int l = idx >> 2, h = idx & 3;
      float s = 0.f;
      const float* wl = Wv + l * HIDN + h * 32;
      for (int dh = 0; dh < 32; dh++) s += wl[dh];
      swvs[idx] = s;
    }
    __syncthreads();
    if (t < 128) {
      int i = t >> 2, h = t & 3;
      float a = 0.f;
      for (int l = 0; l < HIDN; l++) a = fmaf(W2[i * HIDN + l], swvs[l * 4 + h], a);
      Wvsp[t] = a;
    } else if (t < 132) {
      int h = t - 128;
      float a = 0.f;
      for (int l = 0; l < HIDN; l++) a = fmaf(b2[l], swvs[l * 4 + h], a);
      bvs[h] = a;
    }
    return;
  }
  int idx = blockIdx.x * 256 + t;
  if (idx < 8192) {
    int q = idx < 4096;
    int tt = q ? idx : idx - 4096;
    int i = tt >> 7, j = tt & 127;
    const float* W = q ? Wq : Wk;
    float a = 0.f;
    for (int l = 0; l < HIDN; l++)
      a = fmaf(W2[i * HIDN + l], W[l * HIDN + j], a);
    (q ? Wqp : Wkp)[tt] = a;
  } else if (idx < 8320) {
    int j = idx - 8192;
    float a = 0.f;
    for (int l = 0; l < HIDN; l++)
      a = fmaf(b2[l], Wq[l * HIDN + j], a);
    bqp[j] = a;
  }
}

// ---------- K_front (512 threads): partitions first, then edge MLP, then prep2 tail ----------
// Two-pass LDS multi-split is deliberate: bin-grouped writes coalesce; direct per-edge
// scatter (round-1) doubled k_front time via write-allocate on random 4B stores.
// CHUNK=16384 deliberate: 10.5 entries/bin/chunk -> WRITE 77->40MB (round-6 measured).
// 512 threads deliberate: 256thr/64-item blocks = 98 serial poles (R6, 104us); 1024thr = 16
// racing waves reopen lines (R7, WRITE 73MB). 512 = middle: 32 items/thread, 8 waves.
// u32 entries: pair = edLocal(8b)<<19 | es (es<2^19); node = ndLocal(7b)<<16 | ns (ns<2^16).
__global__ __launch_bounds__(512, 8) void k_front(
    const float* __restrict__ x, const int* __restrict__ eidx, const float* __restrict__ ea,
    const float* __restrict__ W1, const float* __restrict__ b1,
    const float* __restrict__ Wvsp, const float* __restrict__ bvs,
    unsigned* __restrict__ embB, uint2* __restrict__ vsb,
    const int* __restrict__ e2e, int* __restrict__ goffP, unsigned* __restrict__ partP,
    const int* __restrict__ n2n, int* __restrict__ goffN, unsigned* __restrict__ partN,
    const float* __restrict__ Wqp, const float* __restrict__ Wkp, const float* __restrict__ bqp,
    const float* __restrict__ Wq2, const float* __restrict__ Wk2, const float* __restrict__ Wv2,
    unsigned short* __restrict__ MBpk, float* __restrict__ c2th,
    float* __restrict__ dhd, float* __restrict__ wv2s,
    int E, int EE, int C, int N, int nEdgeB, int nPartP, int nPartN, int PBINS, int NBINS)
{
  __shared__ int lcnt[MAXPB];
  __shared__ int lbase[MAXPB];
  int b = blockIdx.x;
  int tid = threadIdx.x;
  if (b < nPartP) {
    // ----- pair partition: multi-split CHUNK pairs by ed>>PSEGSH -----
    int start = b * CHUNK;
    for (int i = tid; i < PBINS; i += 512) lcnt[i] = 0;
    __syncthreads();
#pragma unroll 4
    for (int k = 0; k < CHUNK / 512; k++) {
      int p = start + k * 512 + tid;
      if (p < EE) atomicAdd(&lcnt[e2e[EE + p] >> PSEGSH], 1);
    }
    __syncthreads();
    for (int i = tid; i < PBINS; i += 512) {
      int c = lcnt[i];
      lbase[i] = c ? atomicAdd(&goffP[i], c) : 0;
      lcnt[i] = 0;
    }
    __syncthreads();
#pragma unroll 4
    for (int k = 0; k < CHUNK / 512; k++) {
      int p = start + k * 512 + tid;
      if (p < EE) {
        int es = e2e[p], ed = e2e[EE + p];
        int bin = ed >> PSEGSH;
        int pos = atomicAdd(&lcnt[bin], 1) + lbase[bin];
        if (pos < PBCAP)
          partP[(size_t)bin * PBCAP + pos] =
              ((unsigned)(ed & (PSEG - 1)) << 19) | (unsigned)es;
      }
    }
  } else if (b < nPartP + nPartN) {
    // ----- node partition: multi-split CHUNK entries by nd>>NSEGSH, payload ns index -----
    int start = (b - nPartP) * CHUNK;
    for (int i = tid; i < NBINS; i += 512) lcnt[i] = 0;
    __syncthreads();
#pragma unroll 4
    for (int k = 0; k < CHUNK / 512; k++) {
      int c = start + k * 512 + tid;
      if (c < C) {
        int nd = n2n[C + c];
        if (nd < N) atomicAdd(&lcnt[nd >> NSEGSH], 1);
      }
    }
    __syncthreads();
    for (int i = tid; i < NBINS; i += 512) {
      int c = lcnt[i];
      lbase[i] = c ? atomicAdd(&goffN[i], c) : 0;
      lcnt[i] = 0;
    }
    __syncthreads();
#pragma unroll 4
    for (int k = 0; k < CHUNK / 512; k++) {
      int c = start + k * 512 + tid;
      if (c < C) {
        int ns = n2n[c], nd = n2n[C + c];
        if (nd < N) {
          int bin = nd >> NSEGSH;
          int pos = atomicAdd(&lcnt[bin], 1) + lbase[bin];
          if (pos < NBCAP)
            partN[(size_t)bin * NBCAP + pos] =
                ((unsigned)(nd & (NSEG - 1)) << 16) | (unsigned)ns;
        }
      }
    }
  } else if (b < nPartP + nPartN + nEdgeB) {
    // ----- edge MLP path -----
    int e = (b - nPartP - nPartN) * 512 + tid;
    if (e >= E) return;
    int si = eidx[e], di = eidx[E + e];
    float xs = x[si], xd = x[di];

    const float4* b4  = (const float4*)b1;
    const float4* w0  = (const float4*)W1;
    const float4* w1r = (const float4*)(W1 + 32);
    float4 E0, E1, E2, E3, E4, E5, E6, E7;
#define INIT(i) E##i = f4fma(xs, w0[i], f4fma(xd, w1r[i], b4[i]));
    INIT(0) INIT(1) INIT(2) INIT(3) INIT(4) INIT(5) INIT(6) INIT(7)
#undef INIT
    const float4* ea4 = (const float4*)(ea + (size_t)e * 32);
#define ROW(c, wr) { const float4* w_ = (const float4*)(W1 + (size_t)(wr) * 32); \
  E0 = f4fma(c, w_[0], E0); E1 = f4fma(c, w_[1], E1); E2 = f4fma(c, w_[2], E2); E3 = f4fma(c, w_[3], E3); \
  E4 = f4fma(c, w_[4], E4); E5 = f4fma(c, w_[5], E5); E6 = f4fma(c, w_[6], E6); E7 = f4fma(c, w_[7], E7); }
#pragma unroll
    for (int rb = 0; rb < 8; rb++) {
      float4 v = ea4[rb];
      ROW(v.x, 2 + rb * 4 + 0)
      ROW(v.y, 2 + rb * 4 + 1)
      ROW(v.z, 2 + rb * 4 + 2)
      ROW(v.w, 2 + rb * 4 + 3)
    }
#undef ROW
    E0 = f4max0(E0); E1 = f4max0(E1); E2 = f4max0(E2); E3 = f4max0(E3);
    E4 = f4max0(E4); E5 = f4max0(E5); E6 = f4max0(E6); E7 = f4max0(E7);

    uint4 p0, p1, p2, p3;
    p0.x = pack2(E0.x, E0.y); p0.y = pack2(E0.z, E0.w); p0.z = pack2(E1.x, E1.y); p0.w = pack2(E1.z, E1.w);
    p1.x = pack2(E2.x, E2.y); p1.y = pack2(E2.z, E2.w); p1.z = pack2(E3.x, E3.y); p1.w = pack2(E3.z, E3.w);
    p2.x = pack2(E4.x, E4.y); p2.y = pack2(E4.z, E4.w); p2.z = pack2(E5.x, E5.y); p2.w = pack2(E5.z, E5.w);
    p3.x = pack2(E6.x, E6.y); p3.y = pack2(E6.z, E6.w); p3.z = pack2(E7.x, E7.y); p3.w = pack2(E7.z, E7.w);
    uint4* er = (uint4*)(embB + (size_t)e * 16);
    er[0] = p0; er[1] = p1; er[2] = p2; er[3] = p3;

    const float4* wv = (const float4*)Wvsp;
    float4 vs = *(const float4*)bvs;
#define VK(k) { vs = f4fma(E##k.x, wv[4*k+0], vs); vs = f4fma(E##k.y, wv[4*k+1], vs); \
                vs = f4fma(E##k.z, wv[4*k+2], vs); vs = f4fma(E##k.w, wv[4*k+3], vs); }
    VK(0) VK(1) VK(2) VK(3) VK(4) VK(5) VK(6) VK(7)
#undef VK
    vsb[e] = make_uint2(pack2(vs.x, vs.y), pack2(vs.z, vs.w));
  } else {
    // ----- prep2 tail (inputs from k_prep1, which precedes this kernel) -----
    const float rs = 0.17677669529663687f;  // 1/sqrt(32)
    int idx = (b - nPartP - nPartN - nEdgeB) * 512 + tid;
    if (idx < 4096) {
      int jj = idx & 7, lane = (idx >> 3) & 63, nb = (idx >> 9) & 1, h = idx >> 10;
      int k = (lane >> 4) * 8 + jj;
      int n = nb * 16 + (lane & 15);
      float a = 0.f;
      const float* wq = Wqp + k * HIDN + h * 32;
      const float* wk = Wkp + n * HIDN + h * 32;
      for (int j = 0; j < 32; j++) a = fmaf(wq[j], wk[j], a);
      MBpk[idx] = (unsigned short)bf16r(a * rs);
    } else if (idx < 4224) {
      int t = idx - 4096;
      int h = t >> 5, ip = t & 31;
      float a2 = 0.f;
      for (int j = 0; j < 32; j++)
        a2 = fmaf(bqp[h * 32 + j], Wkp[ip * HIDN + h * 32 + j], a2);
      c2th[h * 32 + ip] = a2 * rs;
    } else if (idx < 4228) {
      int h = idx - 4224;
      float d = 0.f, wsum = 0.f;
      for (int dh = 0; dh < 32; dh++) {
        d = fmaf(Wq2[h * 32 + dh], Wk2[h * 32 + dh], d);
        wsum += Wv2[h * 32 + dh];
      }
      dhd[h]  = d * rs;
      wv2s[h] = wsum;
    }
  }
}

// ---------- K_back: node-bin softmax + pair path, one block = one 256-edge bin ----------
// Pair block covers its whole PSEG=256 bin: the bin scan runs ONCE (x1 redundancy; was x4
// at 64-edge blocks), then MFMA+softmax over 4 sub-tiles of 64 edges reusing the buckets.
// LDS 52KB -> 3 blocks/CU.
__global__ __launch_bounds__(256, 3) void k_back(
    const unsigned* __restrict__ embB, const unsigned short* __restrict__ MBpk,
    const uint2* __restrict__ vsb, const float* __restrict__ c2th,
    const int* __restrict__ goffP, const unsigned* __restrict__ partP,
    const int* __restrict__ goffN, const unsigned* __restrict__ partN,
    const float* __restrict__ x, const float* __restrict__ dhd, const float* __restrict__ wv2s,
    float* __restrict__ out0, float* __restrict__ out1,
    int E, int N, int NBINS)
{
  __shared__ float qtl[256 * 33];   // pair: qt tile (one 64-edge sub-tile); node: cnt[128]+rows[128][65]
  __shared__ int pcntL[256];        // pair: per-edge bucket count (whole bin)
  __shared__ int prows[256 * 17];   // pair: bucket rows, padded stride 17
  int b = blockIdx.x;
  int tid = threadIdx.x;
  if (b < NBINS) {
    // ----- node bin: stage partN (u32: s<<16|ns) into padded LDS, gathering x[ns] from L2 -----
    int seg0 = b << NSEGSH;
    int nseg = N - seg0; if (nseg > NSEG) nseg = NSEG;
    int* cnt = (int*)qtl;              // [NSEG]
    float* rows = qtl + NSEG;          // [NSEG][NCAP+1]: bank=(s+n)&31 — conflict-free reads
    for (int i = tid; i < nseg; i += 256) cnt[i] = 0;
    __syncthreads();
    int g = goffN[b]; if (g > NBCAP) g = NBCAP;
    for (int i = tid; i < g; i += 256) {
      unsigned pk = partN[(size_t)b * NBCAP + i];
      int s = (int)(pk >> 16);
      float val = x[pk & 0xFFFFu];
      int pos = atomicAdd(&cnt[s], 1);
      if (pos < NCAP) rows[s * (NCAP + 1) + pos] = val;
    }
    __syncthreads();
    for (int t = tid; t < nseg * 4; t += 256) {
      int s = t >> 2, h = t & 3;
      int c = cnt[s]; c = c < NCAP ? c : NCAP;
      int nd = seg0 + s;
      float xn = x[nd];
      float d = dhd[h];
      const float* bkt = rows + s * (NCAP + 1);

      float amx = -3.4e38f, amn = 3.4e38f;
      for (int n = 0; n < c; n++) {
        float a = xn * bkt[n];
        amx = fmaxf(amx, a); amn = fminf(amn, a);
      }
      float m = (d > 0.f) ? d * amx : d * amn;

      float den = 0.f, num = 0.f;
      for (int n = 0; n < c; n++) {
        float asv = bkt[n];
        float ev = __expf(fmaf(xn * asv, d, -m));
        den += ev;
        num = fmaf(ev, asv, num);
      }
      float r = wv2s[h] * num / (den + 1e-16f);
      r += __shfl_xor(r, 1);
      r += __shfl_xor(r, 2);
      if (h == 0) out0[nd] = r * 0.0078125f;   // 1/128
    }
  } else {
    // ----- pair path: scan own bin ONCE -> LDS buckets for 256 edges; then 4 sub-tiles of
    //       {MFMA qt -> LDS; softmax per (e,h)} -----
    int bin = b - NBINS;
    int wave = tid >> 6, lane = tid & 63;
    int e0 = bin << PSEGSH;

    pcntL[tid] = 0;
    __syncthreads();

    int g = goffP[bin]; if (g > PBCAP) g = PBCAP;
    const unsigned* binp = partP + (size_t)bin * PBCAP;
    for (int i = tid; i < g; i += 256) {
      unsigned pk = binp[i];
      int s = (int)(pk >> 19);           // edLocal, 0..255
      int pos = atomicAdd(&pcntL[s], 1);
      if (pos < PCAP) prows[s * 17 + pos] = (int)(pk & 0x7FFFFu);
    }

    for (int st = 0; st < 4; st++) {
      __syncthreads();   // st==0: scan done / st>0: previous softmax done reading qtl

      // MFMA qt for sub-tile st (64 edges)
      int we0 = e0 + st * 64 + wave * 16;
      union { uint4 u; bf16x8 bv; } af;
      af.u = *((const uint4*)(embB + ((size_t)(we0 + (lane & 15)) << 4)) + (lane >> 4));
#pragma unroll
      for (int hh = 0; hh < 4; hh++) {
#pragma unroll
        for (int nb = 0; nb < 2; nb++) {
          union { uint4 u; bf16x8 bv; } bf;
          bf.u = *(const uint4*)(MBpk + (((hh * 2 + nb) * 64 + lane) << 3));
          int col = nb * 16 + (lane & 15);
          float c2v = c2th[hh * 32 + col];
          f32x4 acc = {c2v, c2v, c2v, c2v};
          acc = __builtin_amdgcn_mfma_f32_16x16x32_bf16(af.bv, bf.bv, acc, 0, 0, 0);
          int rowb = wave * 16 + (lane >> 4) * 4;
#pragma unroll
          for (int r = 0; r < 4; r++)
            qtl[((rowb + r) * 4 + hh) * 33 + col] = acc[r];
        }
      }
      __syncthreads();   // qt ready

      int sloc = st * 64 + (tid >> 2);       // edge index within bin
      int e = e0 + sloc;
      if (e < E) {
        int h = tid & 3;
        const float* q = qtl + tid * 33;
        const int* rowp = prows + sloc * 17;

        int cnt = pcntL[sloc];
        cnt = cnt < PCAP ? cnt : PCAP;

        int s0 = (cnt > 0) ? rowp[0] : 0;
        int s1 = (cnt > 1) ? rowp[1] : 0;
        int s2 = (cnt > 2) ? rowp[2] : 0;
        int s3 = (cnt > 3) ? rowp[3] : 0;
#define GATH(i) \
        const uint4* ep##i = (const uint4*)(embB + ((size_t)s##i << 4)); \
        uint4 u##i##0 = ep##i[0], u##i##1 = ep##i[1], u##i##2 = ep##i[2], u##i##3 = ep##i[3]; \
        uint2 vu##i = vsb[s##i];
        GATH(0) GATH(1) GATH(2) GATH(3)
#undef GATH

        float den = 0.f, num = 0.f;
#define DOT8(uu, base) \
        dot = fmaf(q[base + 0], blo(uu.x), dot); dot = fmaf(q[base + 1], bhi(uu.x), dot); \
        dot = fmaf(q[base + 2], blo(uu.y), dot); dot = fmaf(q[base + 3], bhi(uu.y), dot); \
        dot = fmaf(q[base + 4], blo(uu.z), dot); dot = fmaf(q[base + 5], bhi(uu.z), dot); \
        dot = fmaf(q[base + 6], blo(uu.w), dot); dot = fmaf(q[base + 7], bhi(uu.w), dot);
#define SLOT(i) { \
        float dot = 0.f; \
        DOT8(u##i##0, 0) DOT8(u##i##1, 8) DOT8(u##i##2, 16) DOT8(u##i##3, 24) \
        unsigned vh = (h & 2) ? vu##i.y : vu##i.x; \
        float vsv = (h & 1) ? bhi(vh) : blo(vh); \
        float ex = (i < cnt) ? __expf(dot) : 0.f; \
        den += ex; \
        num = fmaf(ex, vsv, num); }
        SLOT(0) SLOT(1) SLOT(2) SLOT(3)
#undef SLOT

        // rare tail (P(cnt>4) ~5%): serial, indices from LDS
        for (int n = 4; n < cnt; n++) {
          int es = rowp[n];
          const uint4* ep = (const uint4*)(embB + ((size_t)es << 4));
          uint4 t0 = ep[0], t1 = ep[1], t2 = ep[2], t3 = ep[3];
          uint2 vu = vsb[es];
          unsigned vh = (h & 2) ? vu.y : vu.x;
          float vsv = (h & 1) ? bhi(vh) : blo(vh);
          float dot = 0.f;
          DOT8(t0, 0) DOT8(t1, 8) DOT8(t2, 16) DOT8(t3, 24)
          float ex = __expf(dot);
          den += ex;
          num = fmaf(ex, vsv, num);
        }
#undef DOT8

        float r = num / (den + 1e-16f);
        r += __shfl_xor(r, 1);
        r += __shfl_xor(r, 2);
        if (h == 0) out1[e] = r * 0.0078125f;   // 1/128
      }
    }
  }
}

extern "C" void kernel_launch(void* const* d_in, const int* in_sizes, int n_in,
                              void* d_out, int out_size, void* d_ws, size_t ws_size,
                              hipStream_t stream)
{
  const float* x   = (const float*)d_in[0];
  const int*   eidx= (const int*)d_in[1];
  const float* ea  = (const float*)d_in[2];
  const int*   e2e = (const int*)d_in[3];
  const int*   n2n = (const int*)d_in[4];
  const float* W1  = (const float*)d_in[5];
  const float* b1  = (const float*)d_in[6];
  const float* W2  = (const float*)d_in[7];
  const float* b2  = (const float*)d_in[8];
  const float* Wq  = (const float*)d_in[9];
  const float* Wk  = (const float*)d_in[10];
  const float* Wv  = (const float*)d_in[11];
  const float* Wq2 = (const float*)d_in[12];
  const float* Wk2 = (const float*)d_in[13];
  const float* Wv2 = (const float*)d_in[14];

  const int N  = in_sizes[0];        // x is [N,1]  (N < 2^16 assumed by partN packing)
  const int E  = in_sizes[1] / 2;    // E < 2^19 assumed by partP packing
  const int EE = in_sizes[3] / 2;
  const int C  = in_sizes[4] / 2;

  float* out0 = (float*)d_out;       // [N]
  float* out1 = (float*)d_out + N;   // [E]

  const int PBINS = (E + PSEG - 1) >> PSEGSH;   // 1563 for E=400k
  const int NBINS = (N + NSEG - 1) >> NSEGSH;   // 391 for N=50k

  char* w = (char*)d_ws;
  size_t off = 0;
  auto alloc = [&](size_t bytes) -> char* {
    char* p = w + off;
    off += (bytes + 255) & ~(size_t)255;
    return p;
  };
  float* Wqp   = (float*)alloc(EMBN * HIDN * 4);
  float* Wkp   = (float*)alloc(EMBN * HIDN * 4);
  float* bqp   = (float*)alloc(HIDN * 4);
  unsigned short* MBpk = (unsigned short*)alloc(4096 * 2);
  float* c2th  = (float*)alloc(4 * EMBN * 4);
  float* Wvsp  = (float*)alloc(EMBN * 4 * 4);
  float* bvs   = (float*)alloc(16);
  float* dhd   = (float*)alloc(16);
  float* wv2s  = (float*)alloc(16);
  unsigned* embB = (unsigned*)alloc((size_t)E * 16 * 4);        // 25.6 MB
  uint2* vsb   = (uint2*)alloc((size_t)E * 8);                  // 3.2 MB
  unsigned* partP = (unsigned*)alloc((size_t)PBINS * PBCAP * 4);// 4.8 MB (u32 packed)
  unsigned* partN = (unsigned*)alloc((size_t)NBINS * NBCAP * 4);// 4.4 MB (u32 packed)
  int*   goffP = (int*)alloc((size_t)PBINS * 4);                // zeroed by k_prep1 blk 34
  int*   goffN = (int*)alloc((size_t)NBINS * 4);

  const int nEdgeB = (E + 511) / 512;            // 782
  const int nPartP = (EE + CHUNK - 1) / CHUNK;   // 49
  const int nPartN = (C + CHUNK - 1) / CHUNK;    // 49
  const int nPrep2B = 9;                         // 4228 items @ 512/block

  k_prep1<<<35, 256, 0, stream>>>(W2, b2, Wq, Wk, Wv, Wqp, Wkp, bqp, Wvsp, bvs,
                                  goffP, goffN, PBINS, NBINS);
  k_front<<<nPartP + nPartN + nEdgeB + nPrep2B, 512, 0, stream>>>(
      x, eidx, ea, W1, b1, Wvsp, bvs, embB, vsb,
      e2e, goffP, partP, n2n, goffN, partN,
      Wqp, Wkp, bqp, Wq2, Wk2, Wv2, MBpk, c2th, dhd, wv2s,
      E, EE, C, N, nEdgeB, nPartP, nPartN, PBINS, NBINS);
  k_back<<<NBINS + PBINS, 256, 0, stream>>>(
      embB, MBpk, vsb, c2th, goffP, partP, goffN, partN,
      x, dhd, wv2s, out0, out1, E, N, NBINS);
}

// Round 9
// 220.853 us; speedup vs baseline: 1.1106x; 1.1106x over previous
//
#include <hip/hip_runtime.h>
#include <stdint.h>

#define HIDN 128
#define EMBN 32
#define PCAP 16        // pair bucket row (Poisson(2): overflow ~0)
#define NCAP 64        // node bucket row (Poisson(16): overflow ~0)
#define PSEGSH 8       // pair bin = ed >> 8 (256 edges/bin; back 64-edge blocks scan x4)
#define NSEGSH 7       // node bin = nd >> 7   (128 nodes/bin)
#define PSEG (1 << PSEGSH)
#define NSEG (1 << NSEGSH)
#define PBCAP 768      // entries/pair-bin cap (mean 512, +11 sigma)
#define NBCAP 2816     // entries/node-bin cap (mean 2048)
#define CHUNK 8192     // items per partition block: 5.2 entries/bin/chunk (R5's proven ratio)
#define MAXPB 1600     // >= PBINS (1563)

typedef __attribute__((ext_vector_type(8))) short bf16x8;
typedef __attribute__((ext_vector_type(4))) float f32x4;

// ---------- helpers ----------
__device__ __forceinline__ unsigned bf16r(float f) {   // fp32 -> bf16 bits, RNE
  unsigned u = __float_as_uint(f);
  return (u + 0x7FFFu + ((u >> 16) & 1u)) >> 16;
}
__device__ __forceinline__ unsigned pack2(float a, float b) {
  return bf16r(a) | (bf16r(b) << 16);
}
__device__ __forceinline__ float blo(unsigned u) { return __uint_as_float(u << 16); }
__device__ __forceinline__ float bhi(unsigned u) { return __uint_as_float(u & 0xFFFF0000u); }
__device__ __forceinline__ float4 f4fma(float s, float4 a, float4 b) {
  return make_float4(fmaf(s, a.x, b.x), fmaf(s, a.y, b.y), fmaf(s, a.z, b.z), fmaf(s, a.w, b.w));
}
__device__ __forceinline__ float4 f4max0(float4 a) {
  return make_float4(fmaxf(a.x, 0.f), fmaxf(a.y, 0.f), fmaxf(a.z, 0.f), fmaxf(a.w, 0.f));
}

// ---------- prep1: Wq'=W2@Wq, Wk'=W2@Wk, bqp; block 33: Wvsp/bvs; block 34: zero goff ----------
__global__ __launch_bounds__(256) void k_prep1(
    const float* __restrict__ W2, const float* __restrict__ b2,
    const float* __restrict__ Wq, const float* __restrict__ Wk, const float* __restrict__ Wv,
    float* __restrict__ Wqp, float* __restrict__ Wkp, float* __restrict__ bqp,
    float* __restrict__ Wvsp, float* __restrict__ bvs,
    int* __restrict__ goffP, int* __restrict__ goffN, int PBINS, int NBINS)
{
  __shared__ float swvs[HIDN * 4];
  int t = threadIdx.x;
  if (blockIdx.x == 34) {
    // zero bin offset arrays (replaces a hipMemsetAsync dispatch)
    for (int i = t; i < PBINS + NBINS; i += 256) {
      if (i < PBINS) goffP[i] = 0; else goffN[i - PBINS] = 0;
    }
    return;
  }
  if (blockIdx.x == 33) {
    for (int idx = t; idx < HIDN * 4; idx += 256) {
      int l = idx >> 2, h = idx & 3;
      float s = 0.f;
      const float* wl = Wv + l * HIDN + h * 32;
      for (int dh = 0; dh < 32; dh++) s += wl[dh];
      swvs[idx] = s;
    }
    __syncthreads();
    if (t < 128) {
      int i = t >> 2, h = t & 3;
      float a = 0.f;
      for (int l = 0; l < HIDN; l++) a = fmaf(W2[i * HIDN + l], swvs[l * 4 + h], a);
      Wvsp[t] = a;
    } else if (t < 132) {
      int h = t - 128;
      float a = 0.f;
      for (int l = 0; l < HIDN; l++) a = fmaf(b2[l], swvs[l * 4 + h], a);
      bvs[h] = a;
    }
    return;
  }
  int idx = blockIdx.x * 256 + t;
  if (idx < 8192) {
    int q = idx < 4096;
    int tt = q ? idx : idx - 4096;
    int i = tt >> 7, j = tt & 127;
    const float* W = q ? Wq : Wk;
    float a = 0.f;
    for (int l = 0; l < HIDN; l++)
      a = fmaf(W2[i * HIDN + l], W[l * HIDN + j], a);
    (q ? Wqp : Wkp)[tt] = a;
  } else if (idx < 8320) {
    int j = idx - 8192;
    float a = 0.f;
    for (int l = 0; l < HIDN; l++)
      a = fmaf(b2[l], Wq[l * HIDN + j], a);
    bqp[j] = a;
  }
}

// ---------- K_front (256 threads): partitions first, then edge MLP, then prep2 tail ----------
// Two-pass LDS multi-split is deliberate: bin-grouped writes coalesce; direct per-edge
// scatter (round-1) doubled k_front time via write-allocate on random 4B stores.
// CHUNK=8192 deliberate: 8192/1563 = 5.2 entries/bin/chunk — the exact ratio of R5's
// fastest front (66us). Thread-count sweep at CHUNK=16384 (R6/R7/R8: 104/78/86us) showed
// many shallow 256-thr blocks beat deep or wide ones; 8192@256thr = 32 items/thread,
// 98+98 partition blocks overlapping 1563 MLP blocks.
// launch_bounds(256,4) deliberate: occ-8 added ~+17MB write-allocate amplification (R3/R4).
// u32 entries: pair = edLocal(8b)<<19 | es (es<2^19); node = ndLocal(7b)<<16 | ns (ns<2^16).
__global__ __launch_bounds__(256, 4) void k_front(
    const float* __restrict__ x, const int* __restrict__ eidx, const float* __restrict__ ea,
    const float* __restrict__ W1, const float* __restrict__ b1,
    const float* __restrict__ Wvsp, const float* __restrict__ bvs,
    unsigned* __restrict__ embB, uint2* __restrict__ vsb,
    const int* __restrict__ e2e, int* __restrict__ goffP, unsigned* __restrict__ partP,
    const int* __restrict__ n2n, int* __restrict__ goffN, unsigned* __restrict__ partN,
    const float* __restrict__ Wqp, const float* __restrict__ Wkp, const float* __restrict__ bqp,
    const float* __restrict__ Wq2, const float* __restrict__ Wk2, const float* __restrict__ Wv2,
    unsigned short* __restrict__ MBpk, float* __restrict__ c2th,
    float* __restrict__ dhd, float* __restrict__ wv2s,
    int E, int EE, int C, int N, int nEdgeB, int nPartP, int nPartN, int PBINS, int NBINS)
{
  __shared__ int lcnt[MAXPB];
  __shared__ int lbase[MAXPB];
  int b = blockIdx.x;
  int tid = threadIdx.x;
  if (b < nPartP) {
    // ----- pair partition: multi-split CHUNK pairs by ed>>PSEGSH -----
    int start = b * CHUNK;
    for (int i = tid; i < PBINS; i += 256) lcnt[i] = 0;
    __syncthreads();
#pragma unroll 4
    for (int k = 0; k < CHUNK / 256; k++) {
      int p = start + k * 256 + tid;
      if (p < EE) atomicAdd(&lcnt[e2e[EE + p] >> PSEGSH], 1);
    }
    __syncthreads();
    for (int i = tid; i < PBINS; i += 256) {
      int c = lcnt[i];
      lbase[i] = c ? atomicAdd(&goffP[i], c) : 0;
      lcnt[i] = 0;
    }
    __syncthreads();
#pragma unroll 4
    for (int k = 0; k < CHUNK / 256; k++) {
      int p = start + k * 256 + tid;
      if (p < EE) {
        int es = e2e[p], ed = e2e[EE + p];
        int bin = ed >> PSEGSH;
        int pos = atomicAdd(&lcnt[bin], 1) + lbase[bin];
        if (pos < PBCAP)
          partP[(size_t)bin * PBCAP + pos] =
              ((unsigned)(ed & (PSEG - 1)) << 19) | (unsigned)es;
      }
    }
  } else if (b < nPartP + nPartN) {
    // ----- node partition: multi-split CHUNK entries by nd>>NSEGSH, payload ns index -----
    int start = (b - nPartP) * CHUNK;
    for (int i = tid; i < NBINS; i += 256) lcnt[i] = 0;
    __syncthreads();
#pragma unroll 4
    for (int k = 0; k < CHUNK / 256; k++) {
      int c = start + k * 256 + tid;
      if (c < C) {
        int nd = n2n[C + c];
        if (nd < N) atomicAdd(&lcnt[nd >> NSEGSH], 1);
      }
    }
    __syncthreads();
    for (int i = tid; i < NBINS; i += 256) {
      int c = lcnt[i];
      lbase[i] = c ? atomicAdd(&goffN[i], c) : 0;
      lcnt[i] = 0;
    }
    __syncthreads();
#pragma unroll 4
    for (int k = 0; k < CHUNK / 256; k++) {
      int c = start + k * 256 + tid;
      if (c < C) {
        int ns = n2n[c], nd = n2n[C + c];
        if (nd < N) {
          int bin = nd >> NSEGSH;
          int pos = atomicAdd(&lcnt[bin], 1) + lbase[bin];
          if (pos < NBCAP)
            partN[(size_t)bin * NBCAP + pos] =
                ((unsigned)(nd & (NSEG - 1)) << 16) | (unsigned)ns;
        }
      }
    }
  } else if (b < nPartP + nPartN + nEdgeB) {
    // ----- edge MLP path -----
    int e = (b - nPartP - nPartN) * 256 + tid;
    if (e >= E) return;
    int si = eidx[e], di = eidx[E + e];
    float xs = x[si], xd = x[di];

    const float4* b4  = (const float4*)b1;
    const float4* w0  = (const float4*)W1;
    const float4* w1r = (const float4*)(W1 + 32);
    float4 E0, E1, E2, E3, E4, E5, E6, E7;
#define INIT(i) E##i = f4fma(xs, w0[i], f4fma(xd, w1r[i], b4[i]));
    INIT(0) INIT(1) INIT(2) INIT(3) INIT(4) INIT(5) INIT(6) INIT(7)
#undef INIT
    const float4* ea4 = (const float4*)(ea + (size_t)e * 32);
#define ROW(c, wr) { const float4* w_ = (const float4*)(W1 + (size_t)(wr) * 32); \
  E0 = f4fma(c, w_[0], E0); E1 = f4fma(c, w_[1], E1); E2 = f4fma(c, w_[2], E2); E3 = f4fma(c, w_[3], E3); \
  E4 = f4fma(c, w_[4], E4); E5 = f4fma(c, w_[5], E5); E6 = f4fma(c, w_[6], E6); E7 = f4fma(c, w_[7], E7); }
#pragma unroll
    for (int rb = 0; rb < 8; rb++) {
      float4 v = ea4[rb];
      ROW(v.x, 2 + rb * 4 + 0)
      ROW(v.y, 2 + rb * 4 + 1)
      ROW(v.z, 2 + rb * 4 + 2)
      ROW(v.w, 2 + rb * 4 + 3)
    }
#undef ROW
    E0 = f4max0(E0); E1 = f4max0(E1); E2 = f4max0(E2); E3 = f4max0(E3);
    E4 = f4max0(E4); E5 = f4max0(E5); E6 = f4max0(E6); E7 = f4max0(E7);

    uint4 p0, p1, p2, p3;
    p0.x = pack2(E0.x, E0.y); p0.y = pack2(E0.z, E0.w); p0.z = pack2(E1.x, E1.y); p0.w = pack2(E1.z, E1.w);
    p1.x = pack2(E2.x, E2.y); p1.y = pack2(E2.z, E2.w); p1.z = pack2(E3.x, E3.y); p1.w = pack2(E3.z, E3.w);
    p2.x = pack2(E4.x, E4.y); p2.y = pack2(E4.z, E4.w); p2.z = pack2(E5.x, E5.y); p2.w = pack2(E5.z, E5.w);
    p3.x = pack2(E6.x, E6.y); p3.y = pack2(E6.z, E6.w); p3.z = pack2(E7.x, E7.y); p3.w = pack2(E7.z, E7.w);
    uint4* er = (uint4*)(embB + (size_t)e * 16);
    er[0] = p0; er[1] = p1; er[2] = p2; er[3] = p3;

    const float4* wv = (const float4*)Wvsp;
    float4 vs = *(const float4*)bvs;
#define VK(k) { vs = f4fma(E##k.x, wv[4*k+0], vs); vs = f4fma(E##k.y, wv[4*k+1], vs); \
                vs = f4fma(E##k.z, wv[4*k+2], vs); vs = f4fma(E##k.w, wv[4*k+3], vs); }
    VK(0) VK(1) VK(2) VK(3) VK(4) VK(5) VK(6) VK(7)
#undef VK
    vsb[e] = make_uint2(pack2(vs.x, vs.y), pack2(vs.z, vs.w));
  } else {
    // ----- prep2 tail (inputs from k_prep1, which precedes this kernel) -----
    const float rs = 0.17677669529663687f;  // 1/sqrt(32)
    int idx = (b - nPartP - nPartN - nEdgeB) * 256 + tid;
    if (idx < 4096) {
      int jj = idx & 7, lane = (idx >> 3) & 63, nb = (idx >> 9) & 1, h = idx >> 10;
      int k = (lane >> 4) * 8 + jj;
      int n = nb * 16 + (lane & 15);
      float a = 0.f;
      const float* wq = Wqp + k * HIDN + h * 32;
      const float* wk = Wkp + n * HIDN + h * 32;
      for (int j = 0; j < 32; j++) a = fmaf(wq[j], wk[j], a);
      MBpk[idx] = (unsigned short)bf16r(a * rs);
    } else if (idx < 4224) {
      int t = idx - 4096;
      int h = t >> 5, ip = t & 31;
      float a2 = 0.f;
      for (int j = 0; j < 32; j++)
        a2 = fmaf(bqp[h * 32 + j], Wkp[ip * HIDN + h * 32 + j], a2);
      c2th[h * 32 + ip] = a2 * rs;
    } else if (idx < 4228) {
      int h = idx - 4224;
      float d = 0.f, wsum = 0.f;
      for (int dh = 0; dh < 32; dh++) {
        d = fmaf(Wq2[h * 32 + dh], Wk2[h * 32 + dh], d);
        wsum += Wv2[h * 32 + dh];
      }
      dhd[h]  = d * rs;
      wv2s[h] = wsum;
    }
  }
}

// ---------- K_back: node-bin softmax + pair path (R7 config: 64-edge blocks, x4 scan) ----------
// Pair block (64 edges) scans its 256-edge bin (mean 512 u32 entries, L2-hot, x4 redundancy).
// R8 measured the whole-bin x1-scan variant at ~58us vs this ~53us: block-parallelism +
// no subtile serialization beats the extra scan reads.
__global__ __launch_bounds__(256, 4) void k_back(
    const unsigned* __restrict__ embB, const unsigned short* __restrict__ MBpk,
    const uint2* __restrict__ vsb, const float* __restrict__ c2th,
    const int* __restrict__ goffP, const unsigned* __restrict__ partP,
    const int* __restrict__ goffN, const unsigned* __restrict__ partN,
    const float* __restrict__ x, const float* __restrict__ dhd, const float* __restrict__ wv2s,
    float* __restrict__ out0, float* __restrict__ out1,
    int E, int N, int NBINS)
{
  __shared__ float qtl[256 * 33];   // pair: qt tile; node: aliased as cnt[128] + rows[128][65] (8448 floats)
  __shared__ int pcntL[64];         // pair: per-edge bucket count
  __shared__ int prows[64 * 17];    // pair: bucket rows, padded 16->17 (conflict-free, stride 17)
  int b = blockIdx.x;
  int tid = threadIdx.x;
  if (b < NBINS) {
    // ----- node bin: stage partN (u32: s<<16|ns) into padded LDS, gathering x[ns] from L2 -----
    int seg0 = b << NSEGSH;
    int nseg = N - seg0; if (nseg > NSEG) nseg = NSEG;
    int* cnt = (int*)qtl;              // [NSEG]
    float* rows = qtl + NSEG;          // [NSEG][NCAP+1]: bank=(s+n)&31 — conflict-free reads
    for (int i = tid; i < nseg; i += 256) cnt[i] = 0;
    __syncthreads();
    int g = goffN[b]; if (g > NBCAP) g = NBCAP;
    for (int i = tid; i < g; i += 256) {
      unsigned pk = partN[(size_t)b * NBCAP + i];
      int s = (int)(pk >> 16);
      float val = x[pk & 0xFFFFu];
      int pos = atomicAdd(&cnt[s], 1);
      if (pos < NCAP) rows[s * (NCAP + 1) + pos] = val;
    }
    __syncthreads();
    for (int t = tid; t < nseg * 4; t += 256) {
      int s = t >> 2, h = t & 3;
      int c = cnt[s]; c = c < NCAP ? c : NCAP;
      int nd = seg0 + s;
      float xn = x[nd];
      float d = dhd[h];
      const float* bkt = rows + s * (NCAP + 1);

      float amx = -3.4e38f, amn = 3.4e38f;
      for (int n = 0; n < c; n++) {
        float a = xn * bkt[n];
        amx = fmaxf(amx, a); amn = fminf(amn, a);
      }
      float m = (d > 0.f) ? d * amx : d * amn;

      float den = 0.f, num = 0.f;
      for (int n = 0; n < c; n++) {
        float asv = bkt[n];
        float ev = __expf(fmaf(xn * asv, d, -m));
        den += ev;
        num = fmaf(ev, asv, num);
      }
      float r = wv2s[h] * num / (den + 1e-16f);
      r += __shfl_xor(r, 1);
      r += __shfl_xor(r, 2);
      if (h == 0) out0[nd] = r * 0.0078125f;   // 1/128
    }
  } else {
    // ----- pair path: scan bin (u32: edLocal<<19|es) -> LDS bucket; MFMA qt -> LDS; softmax -----
    int pb = b - NBINS;
    int wave = tid >> 6, lane = tid & 63;
    int e0 = pb * 64;
    int bin = e0 >> PSEGSH;
    int eloc0 = e0 & (PSEG - 1);
    int we0 = e0 + wave * 16;

    if (tid < 64) pcntL[tid] = 0;

    union { uint4 u; bf16x8 bv; } af;
    af.u = *((const uint4*)(embB + ((size_t)(we0 + (lane & 15)) << 4)) + (lane >> 4));

    __syncthreads();

    // scan this block's bin for entries targeting edges [e0, e0+64)
    int g = goffP[bin]; if (g > PBCAP) g = PBCAP;
    const unsigned* binp = partP + (size_t)bin * PBCAP;
    for (int i = tid; i < g; i += 256) {
      unsigned pk = binp[i];
      unsigned s = (pk >> 19) - (unsigned)eloc0;
      if (s < 64u) {
        int pos = atomicAdd(&pcntL[s], 1);
        if (pos < PCAP) prows[s * 17 + pos] = (int)(pk & 0x7FFFFu);
      }
    }

    // MFMA qt phase (independent of the scan; overlaps its latency)
#pragma unroll
    for (int hh = 0; hh < 4; hh++) {
#pragma unroll
      for (int nb = 0; nb < 2; nb++) {
        union { uint4 u; bf16x8 bv; } bf;
        bf.u = *(const uint4*)(MBpk + (((hh * 2 + nb) * 64 + lane) << 3));
        int col = nb * 16 + (lane & 15);
        float c2v = c2th[hh * 32 + col];
        f32x4 acc = {c2v, c2v, c2v, c2v};
        acc = __builtin_amdgcn_mfma_f32_16x16x32_bf16(af.bv, bf.bv, acc, 0, 0, 0);
        int rowb = wave * 16 + (lane >> 4) * 4;
#pragma unroll
        for (int r = 0; r < 4; r++)
          qtl[((rowb + r) * 4 + hh) * 33 + col] = acc[r];
      }
    }

    __syncthreads();

    int e = e0 + (tid >> 2);
    if (e >= E) return;
    int h = tid & 3;
    const float* q = qtl + tid * 33;
    int sloc = tid >> 2;
    const int* rowp = prows + sloc * 17;

    int cnt = pcntL[sloc];
    cnt = cnt < PCAP ? cnt : PCAP;

    int s0 = (cnt > 0) ? rowp[0] : 0;
    int s1 = (cnt > 1) ? rowp[1] : 0;
    int s2 = (cnt > 2) ? rowp[2] : 0;
    int s3 = (cnt > 3) ? rowp[3] : 0;
#define GATH(i) \
    const uint4* ep##i = (const uint4*)(embB + ((size_t)s##i << 4)); \
    uint4 u##i##0 = ep##i[0], u##i##1 = ep##i[1], u##i##2 = ep##i[2], u##i##3 = ep##i[3]; \
    uint2 vu##i = vsb[s##i];
    GATH(0) GATH(1) GATH(2) GATH(3)
#undef GATH

    float den = 0.f, num = 0.f;
#define DOT8(uu, base) \
      dot = fmaf(q[base + 0], blo(uu.x), dot); dot = fmaf(q[base + 1], bhi(uu.x), dot); \
      dot = fmaf(q[base + 2], blo(uu.y), dot); dot = fmaf(q[base + 3], bhi(uu.y), dot); \
      dot = fmaf(q[base + 4], blo(uu.z), dot); dot = fmaf(q[base + 5], bhi(uu.z), dot); \
      dot = fmaf(q[base + 6], blo(uu.w), dot); dot = fmaf(q[base + 7], bhi(uu.w), dot);
#define SLOT(i) { \
      float dot = 0.f; \
      DOT8(u##i##0, 0) DOT8(u##i##1, 8) DOT8(u##i##2, 16) DOT8(u##i##3, 24) \
      unsigned vh = (h & 2) ? vu##i.y : vu##i.x; \
      float vsv = (h & 1) ? bhi(vh) : blo(vh); \
      float ex = (i < cnt) ? __expf(dot) : 0.f; \
      den += ex; \
      num = fmaf(ex, vsv, num); }
    SLOT(0) SLOT(1) SLOT(2) SLOT(3)
#undef SLOT

    // rare tail (P(cnt>4) ~5%): serial, indices from LDS
    for (int n = 4; n < cnt; n++) {
      int es = rowp[n];
      const uint4* ep = (const uint4*)(embB + ((size_t)es << 4));
      uint4 t0 = ep[0], t1 = ep[1], t2 = ep[2], t3 = ep[3];
      uint2 vu = vsb[es];
      unsigned vh = (h & 2) ? vu.y : vu.x;
      float vsv = (h & 1) ? bhi(vh) : blo(vh);
      float dot = 0.f;
      DOT8(t0, 0) DOT8(t1, 8) DOT8(t2, 16) DOT8(t3, 24)
      float ex = __expf(dot);
      den += ex;
      num = fmaf(ex, vsv, num);
    }
#undef DOT8

    float r = num / (den + 1e-16f);
    r += __shfl_xor(r, 1);
    r += __shfl_xor(r, 2);
    if (h == 0) out1[e] = r * 0.0078125f;   // 1/128
  }
}

extern "C" void kernel_launch(void* const* d_in, const int* in_sizes, int n_in,
                              void* d_out, int out_size, void* d_ws, size_t ws_size,
                              hipStream_t stream)
{
  const float* x   = (const float*)d_in[0];
  const int*   eidx= (const int*)d_in[1];
  const float* ea  = (const float*)d_in[2];
  const int*   e2e = (const int*)d_in[3];
  const int*   n2n = (const int*)d_in[4];
  const float* W1  = (const float*)d_in[5];
  const float* b1  = (const float*)d_in[6];
  const float* W2  = (const float*)d_in[7];
  const float* b2  = (const float*)d_in[8];
  const float* Wq  = (const float*)d_in[9];
  const float* Wk  = (const float*)d_in[10];
  const float* Wv  = (const float*)d_in[11];
  const float* Wq2 = (const float*)d_in[12];
  const float* Wk2 = (const float*)d_in[13];
  const float* Wv2 = (const float*)d_in[14];

  const int N  = in_sizes[0];        // x is [N,1]  (N < 2^16 assumed by partN packing)
  const int E  = in_sizes[1] / 2;    // E < 2^19 assumed by partP packing
  const int EE = in_sizes[3] / 2;
  const int C  = in_sizes[4] / 2;

  float* out0 = (float*)d_out;       // [N]
  float* out1 = (float*)d_out + N;   // [E]

  const int PBINS = (E + PSEG - 1) >> PSEGSH;   // 1563 for E=400k
  const int NBINS = (N + NSEG - 1) >> NSEGSH;   // 391 for N=50k

  char* w = (char*)d_ws;
  size_t off = 0;
  auto alloc = [&](size_t bytes) -> char* {
    char* p = w + off;
    off += (bytes + 255) & ~(size_t)255;
    return p;
  };
  float* Wqp   = (float*)alloc(EMBN * HIDN * 4);
  float* Wkp   = (float*)alloc(EMBN * HIDN * 4);
  float* bqp   = (float*)alloc(HIDN * 4);
  unsigned short* MBpk = (unsigned short*)alloc(4096 * 2);
  float* c2th  = (float*)alloc(4 * EMBN * 4);
  float* Wvsp  = (float*)alloc(EMBN * 4 * 4);
  float* bvs   = (float*)alloc(16);
  float* dhd   = (float*)alloc(16);
  float* wv2s  = (float*)alloc(16);
  unsigned* embB = (unsigned*)alloc((size_t)E * 16 * 4);        // 25.6 MB
  uint2* vsb   = (uint2*)alloc((size_t)E * 8);                  // 3.2 MB
  unsigned* partP = (unsigned*)alloc((size_t)PBINS * PBCAP * 4);// 4.8 MB (u32 packed)
  unsigned* partN = (unsigned*)alloc((size_t)NBINS * NBCAP * 4);// 4.4 MB (u32 packed)
  int*   goffP = (int*)alloc((size_t)PBINS * 4);                // zeroed by k_prep1 blk 34
  int*   goffN = (int*)alloc((size_t)NBINS * 4);

  const int nEdgeB = (E + 255) / 256;            // 1563
  const int nPartP = (EE + CHUNK - 1) / CHUNK;   // 98
  const int nPartN = (C + CHUNK - 1) / CHUNK;    // 98
  const int nPairMfmaB = (E + 63) / 64;          // 6250
  const int nPrep2B = 17;                        // 4228 items @ 256/block

  k_prep1<<<35, 256, 0, stream>>>(W2, b2, Wq, Wk, Wv, Wqp, Wkp, bqp, Wvsp, bvs,
                                  goffP, goffN, PBINS, NBINS);
  k_front<<<nPartP + nPartN + nEdgeB + nPrep2B, 256, 0, stream>>>(
      x, eidx, ea, W1, b1, Wvsp, bvs, embB, vsb,
      e2e, goffP, partP, n2n, goffN, partN,
      Wqp, Wkp, bqp, Wq2, Wk2, Wv2, MBpk, c2th, dhd, wv2s,
      E, EE, C, N, nEdgeB, nPartP, nPartN, PBINS, NBINS);
  k_back<<<NBINS + nPairMfmaB, 256, 0, stream>>>(
      embB, MBpk, vsb, c2th, goffP, partP, goffN, partN,
      x, dhd, wv2s, out0, out1, E, N, NBINS);
}